// Round 3
// baseline (179.222 us; speedup 1.0000x reference)
//
#include <hip/hip_runtime.h>

#pragma clang fp contract(off)

#define IMG_H 512
#define IMG_W 512
#define TILE 64
#define PAD 2
#define LROWS 68
#define LCOLS 70                 // padded float2 width
#define NTHREADS 512

__device__ __forceinline__ int reflect_idx(int i) {
    // jnp.pad 'reflect': -1 -> 1, 512 -> 510
    i = (i < 0) ? -i : i;
    i = (i >= IMG_H) ? (2 * IMG_H - 2 - i) : i;
    return i;
}

__device__ __forceinline__ float2 gray2(float a0, float a1, float a2,
                                        float b0, float b1, float b2) {
    // bit-identical to verified T_a gray conversion
    float2 g;
    g.x = (0.144f * a0 + 0.587f * a1) + 0.299f * a2;
    g.y = (0.144f * b0 + 0.587f * b1) + 0.299f * b2;
    return g;
}

// Stage one 68x68 halo tile of interleaved (gray1,gray2) pairs into buf.
// Interior 64 cols per row: aligned float4 global loads (x0 % 64 == 0).
// 2-col halos: scalar loads with reflect (covers all edge cases).
__device__ __forceinline__ void stage_tile(float2 (*buf)[LCOLS],
        const float* __restrict__ i1, const float* __restrict__ i2,
        int x0, int y0, int tid) {
    const size_t plane = (size_t)IMG_H * IMG_W;

    // ---- interior: 68 rows x 16 quads = 1088 items; 2 full passes + tail ----
    int it0 = tid;
    int it1 = tid + NTHREADS;
    int r0 = it0 >> 4, q0 = it0 & 15;
    int r1 = it1 >> 4, q1 = it1 & 15;
    int gy0 = reflect_idx(y0 + r0 - PAD);
    int gy1 = reflect_idx(y0 + r1 - PAD);
    const float* pa0 = i1 + (size_t)gy0 * IMG_W + (x0 + 4 * q0);
    const float* pb0 = i2 + (size_t)gy0 * IMG_W + (x0 + 4 * q0);
    const float* pa1 = i1 + (size_t)gy1 * IMG_W + (x0 + 4 * q1);
    const float* pb1 = i2 + (size_t)gy1 * IMG_W + (x0 + 4 * q1);

    // issue all 12 dwordx4 loads before any use (single latency exposure)
    float4 A0 = *(const float4*)(pa0);
    float4 A1 = *(const float4*)(pa0 + plane);
    float4 A2 = *(const float4*)(pa0 + 2 * plane);
    float4 B0 = *(const float4*)(pb0);
    float4 B1 = *(const float4*)(pb0 + plane);
    float4 B2 = *(const float4*)(pb0 + 2 * plane);
    float4 C0 = *(const float4*)(pa1);
    float4 C1 = *(const float4*)(pa1 + plane);
    float4 C2 = *(const float4*)(pa1 + 2 * plane);
    float4 D0 = *(const float4*)(pb1);
    float4 D1 = *(const float4*)(pb1 + plane);
    float4 D2 = *(const float4*)(pb1 + 2 * plane);

    {
        float2 g0 = gray2(A0.x, A1.x, A2.x, B0.x, B1.x, B2.x);
        float2 g1 = gray2(A0.y, A1.y, A2.y, B0.y, B1.y, B2.y);
        float2 g2 = gray2(A0.z, A1.z, A2.z, B0.z, B1.z, B2.z);
        float2 g3 = gray2(A0.w, A1.w, A2.w, B0.w, B1.w, B2.w);
        float4* dst = (float4*)&buf[r0][2 + 4 * q0];   // 16B-aligned
        dst[0] = make_float4(g0.x, g0.y, g1.x, g1.y);
        dst[1] = make_float4(g2.x, g2.y, g3.x, g3.y);
    }
    {
        float2 g0 = gray2(C0.x, C1.x, C2.x, D0.x, D1.x, D2.x);
        float2 g1 = gray2(C0.y, C1.y, C2.y, D0.y, D1.y, D2.y);
        float2 g2 = gray2(C0.z, C1.z, C2.z, D0.z, D1.z, D2.z);
        float2 g3 = gray2(C0.w, C1.w, C2.w, D0.w, D1.w, D2.w);
        float4* dst = (float4*)&buf[r1][2 + 4 * q1];
        dst[0] = make_float4(g0.x, g0.y, g1.x, g1.y);
        dst[1] = make_float4(g2.x, g2.y, g3.x, g3.y);
    }

    if (tid < 64) {   // tail items 1024..1087
        int it2 = tid + 1024;
        int r2 = it2 >> 4, q2 = it2 & 15;
        int gy2 = reflect_idx(y0 + r2 - PAD);
        const float* pa2 = i1 + (size_t)gy2 * IMG_W + (x0 + 4 * q2);
        const float* pb2 = i2 + (size_t)gy2 * IMG_W + (x0 + 4 * q2);
        float4 E0 = *(const float4*)(pa2);
        float4 E1 = *(const float4*)(pa2 + plane);
        float4 E2 = *(const float4*)(pa2 + 2 * plane);
        float4 F0 = *(const float4*)(pb2);
        float4 F1 = *(const float4*)(pb2 + plane);
        float4 F2 = *(const float4*)(pb2 + 2 * plane);
        float2 g0 = gray2(E0.x, E1.x, E2.x, F0.x, F1.x, F2.x);
        float2 g1 = gray2(E0.y, E1.y, E2.y, F0.y, F1.y, F2.y);
        float2 g2 = gray2(E0.z, E1.z, E2.z, F0.z, F1.z, F2.z);
        float2 g3 = gray2(E0.w, E1.w, E2.w, F0.w, F1.w, F2.w);
        float4* dst = (float4*)&buf[r2][2 + 4 * q2];
        dst[0] = make_float4(g0.x, g0.y, g1.x, g1.y);
        dst[1] = make_float4(g2.x, g2.y, g3.x, g3.y);
    }

    // ---- halo: 68 rows x 4 cols = 272 items, scalar (handles reflect) ----
    if (tid < 272) {
        int r = tid >> 2, s = tid & 3;
        int c = (s < 2) ? s : (s + 64);      // LDS cols 0,1,66,67
        int gy = reflect_idx(y0 + r - PAD);
        int gx = reflect_idx(x0 + c - PAD);
        size_t off = (size_t)gy * IMG_W + gx;
        float a0 = i1[off], a1 = i1[off + plane], a2 = i1[off + 2 * plane];
        float b0 = i2[off], b1 = i2[off + plane], b2 = i2[off + 2 * plane];
        buf[r][c] = gray2(a0, a1, a2, b0, b1, b2);
    }
}

// T_a chains (verified absmax=0.0): rows ascend, dx ascends within row,
// acc starts 0.0f, mean via s*0.04f recip-mul. Bit-identical to R2.
__device__ __forceinline__ void compute_tile(const float2 (*buf)[LCOLS],
        float* __restrict__ out, int b, int x0, int y0, int tid) {
    const int cx = tid & 31;
    const int ry = tid >> 5;
    const int r0 = ry * 4;
    const int cb = 2 * cx;

    float s1[4][2], q1[4][2], s2[4][2], q2[4][2];
    #pragma unroll
    for (int k = 0; k < 4; ++k) {
        #pragma unroll
        for (int j = 0; j < 2; ++j) {
            s1[k][j] = 0.0f; q1[k][j] = 0.0f;
            s2[k][j] = 0.0f; q2[k][j] = 0.0f;
        }
    }

    #pragma unroll
    for (int rr = 0; rr < 8; ++rr) {
        const float4* vp = (const float4*)&buf[r0 + rr][cb];  // 16B-aligned
        float4 w0 = vp[0], w1 = vp[1], w2 = vp[2];
        float2 v[6];
        v[0] = make_float2(w0.x, w0.y); v[1] = make_float2(w0.z, w0.w);
        v[2] = make_float2(w1.x, w1.y); v[3] = make_float2(w1.z, w1.w);
        v[4] = make_float2(w2.x, w2.y); v[5] = make_float2(w2.z, w2.w);

        #pragma unroll
        for (int k = 0; k < 4; ++k) {
            if (rr >= k && rr <= k + 4) {   // compile-time predicate
                #pragma unroll
                for (int j = 0; j < 2; ++j) {
                    #pragma unroll
                    for (int dx = 0; dx < 5; ++dx) {
                        float a = v[dx + j].x;
                        float c = v[dx + j].y;
                        s1[k][j] = s1[k][j] + a;
                        q1[k][j] = q1[k][j] + a * a;
                        s2[k][j] = s2[k][j] + c;
                        q2[k][j] = q2[k][j] + c * c;
                    }
                }
            }
        }
    }

    #pragma unroll
    for (int k = 0; k < 4; ++k) {
        float2 o;
        #pragma unroll
        for (int j = 0; j < 2; ++j) {
            float m1 = s1[k][j] * 0.04f;
            float e1 = q1[k][j] * 0.04f;
            float m2 = s2[k][j] * 0.04f;
            float e2 = q2[k][j] * 0.04f;
            float var1 = fmaxf(e1 - m1 * m1, 0.0f);
            float sd1 = sqrtf(var1 + 1e-9f);
            float var2 = fmaxf(e2 - m2 * m2, 0.0f);
            float sd2 = sqrtf(var2 + 1e-9f);
            float num = (2.0f * sd1) * sd2;
            float den = ((sd1 * sd1 + sd2 * sd2) + 1e-5f) + 1e-8f;
            float val = (num / den > 0.975f) ? 1.0f : 0.0f;
            (j == 0 ? o.x : o.y) = val;
        }
        size_t oidx = ((size_t)b * IMG_H + (y0 + r0 + k)) * IMG_W + (x0 + cb);
        *reinterpret_cast<float2*>(&out[oidx]) = o;
    }
}

// 2 tiles per block, double-buffered LDS. stage(buf1) and compute(buf0)
// touch disjoint LDS -> no barrier between them: waves interleave HBM
// (staging) with VALU (chains) instead of convoying through phases.
__global__ __launch_bounds__(NTHREADS, 4) void texdiff_kernel(
        const float* __restrict__ img1,
        const float* __restrict__ img2,
        float* __restrict__ out) {
    __shared__ float2 g12[2][LROWS][LCOLS];   // 2 x 38,080 B = 76,160 B

    const int b   = blockIdx.z;
    const int y0  = blockIdx.y * TILE;
    const int x0a = blockIdx.x * (2 * TILE);
    const int x0b = x0a + TILE;
    const int tid = threadIdx.x;

    const size_t plane = (size_t)IMG_H * IMG_W;
    const float* i1 = img1 + (size_t)b * 3 * plane;
    const float* i2 = img2 + (size_t)b * 3 * plane;

    stage_tile(g12[0], i1, i2, x0a, y0, tid);
    __syncthreads();
    stage_tile(g12[1], i1, i2, x0b, y0, tid);   // overlaps with next line
    compute_tile(g12[0], out, b, x0a, y0, tid);
    __syncthreads();
    compute_tile(g12[1], out, b, x0b, y0, tid);
}

extern "C" void kernel_launch(void* const* d_in, const int* in_sizes, int n_in,
                              void* d_out, int out_size, void* d_ws, size_t ws_size,
                              hipStream_t stream) {
    const float* img1 = (const float*)d_in[0];
    const float* img2 = (const float*)d_in[1];
    float* out = (float*)d_out;
    dim3 grid(IMG_W / (2 * TILE), IMG_H / TILE, 16);   // 4 x 8 x 16 = 512 blocks
    texdiff_kernel<<<grid, dim3(NTHREADS), 0, stream>>>(img1, img2, out);
}

// Round 4
// 144.634 us; speedup vs baseline: 1.2391x; 1.2391x over previous
//
#include <hip/hip_runtime.h>

#pragma clang fp contract(off)

#define IMG_H 512
#define IMG_W 512
#define TILE 64
#define PAD 2
#define LROWS 68
#define LCOLS 70                 // padded float2 width (even -> 16B-aligned pairs)
#define NTHREADS 512

__device__ __forceinline__ int reflect_idx(int i) {
    // jnp.pad 'reflect': -1 -> 1, 512 -> 510
    i = (i < 0) ? -i : i;
    i = (i >= IMG_H) ? (2 * IMG_H - 2 - i) : i;
    return i;
}

__device__ __forceinline__ float2 gray2(float a0, float a1, float a2,
                                        float b0, float b1, float b2) {
    // bit-identical T_a gray conversion (verified absmax=0.0)
    float2 g;
    g.x = (0.144f * a0 + 0.587f * a1) + 0.299f * a2;
    g.y = (0.144f * b0 + 0.587f * b1) + 0.299f * b2;
    return g;
}

// One interior staging item = 4 adjacent pixels x {3ch img1, 3ch img2}.
struct Quad { float4 a0, a1, a2, b0, b1, b2; };

__device__ __forceinline__ void load_quad(Quad& Q,
        const float* __restrict__ i1, const float* __restrict__ i2,
        int x0, int y0, int item) {
    const size_t plane = (size_t)IMG_H * IMG_W;
    int r = item >> 4, q = item & 15;
    int gy = reflect_idx(y0 + r - PAD);
    const float* pa = i1 + (size_t)gy * IMG_W + (x0 + 4 * q);
    const float* pb = i2 + (size_t)gy * IMG_W + (x0 + 4 * q);
    Q.a0 = *(const float4*)(pa);
    Q.a1 = *(const float4*)(pa + plane);
    Q.a2 = *(const float4*)(pa + 2 * plane);
    Q.b0 = *(const float4*)(pb);
    Q.b1 = *(const float4*)(pb + plane);
    Q.b2 = *(const float4*)(pb + 2 * plane);
}

__device__ __forceinline__ void write_quad(float2 (*buf)[LCOLS],
        const Quad& Q, int item) {
    int r = item >> 4, q = item & 15;
    float2 g0 = gray2(Q.a0.x, Q.a1.x, Q.a2.x, Q.b0.x, Q.b1.x, Q.b2.x);
    float2 g1 = gray2(Q.a0.y, Q.a1.y, Q.a2.y, Q.b0.y, Q.b1.y, Q.b2.y);
    float2 g2 = gray2(Q.a0.z, Q.a1.z, Q.a2.z, Q.b0.z, Q.b1.z, Q.b2.z);
    float2 g3 = gray2(Q.a0.w, Q.a1.w, Q.a2.w, Q.b0.w, Q.b1.w, Q.b2.w);
    float4* dst = (float4*)&buf[r][2 + 4 * q];   // 16B-aligned
    dst[0] = make_float4(g0.x, g0.y, g1.x, g1.y);
    dst[1] = make_float4(g2.x, g2.y, g3.x, g3.y);
}

// Simple staging (tile A): one item in flight at a time -> low VGPR.
__device__ __forceinline__ void stage_tile(float2 (*buf)[LCOLS],
        const float* __restrict__ i1, const float* __restrict__ i2,
        int x0, int y0, int tid) {
    const size_t plane = (size_t)IMG_H * IMG_W;
    Quad Q;
    load_quad(Q, i1, i2, x0, y0, tid);
    write_quad(buf, Q, tid);
    load_quad(Q, i1, i2, x0, y0, tid + NTHREADS);
    write_quad(buf, Q, tid + NTHREADS);
    if (tid < 64) {
        load_quad(Q, i1, i2, x0, y0, tid + 2 * NTHREADS);
        write_quad(buf, Q, tid + 2 * NTHREADS);
    }
    if (tid < 272) {   // halo: 68 rows x cols {0,1,66,67}
        int r = tid >> 2, s = tid & 3;
        int c = (s < 2) ? s : (s + 64);
        int gy = reflect_idx(y0 + r - PAD);
        int gx = reflect_idx(x0 + c - PAD);
        size_t off = (size_t)gy * IMG_W + gx;
        buf[r][c] = gray2(i1[off], i1[off + plane], i1[off + 2 * plane],
                          i2[off], i2[off + plane], i2[off + 2 * plane]);
    }
}

// T_a fold of one LDS row into the applicable window chains.
// Rows ascend (caller), dx ascends within row -> bit-identical to R2.
#define FOLD_ROW(BUF, RR)                                                    \
    {                                                                        \
        const float4* vp = (const float4*)&BUF[r0 + (RR)][cb];               \
        float4 w0 = vp[0], w1 = vp[1], w2 = vp[2];                           \
        float vx[6], vy[6];                                                  \
        vx[0] = w0.x; vy[0] = w0.y; vx[1] = w0.z; vy[1] = w0.w;              \
        vx[2] = w1.x; vy[2] = w1.y; vx[3] = w1.z; vy[3] = w1.w;              \
        vx[4] = w2.x; vy[4] = w2.y; vx[5] = w2.z; vy[5] = w2.w;              \
        _Pragma("unroll")                                                    \
        for (int k = 0; k < 4; ++k) {                                        \
            if ((RR) >= k && (RR) <= k + 4) {                                \
                _Pragma("unroll")                                            \
                for (int j = 0; j < 2; ++j) {                                \
                    _Pragma("unroll")                                        \
                    for (int dx = 0; dx < 5; ++dx) {                         \
                        float a = vx[dx + j];                                \
                        float c = vy[dx + j];                                \
                        s1[k][j] = s1[k][j] + a;  q1[k][j] = q1[k][j] + a*a; \
                        s2[k][j] = s2[k][j] + c;  q2[k][j] = q2[k][j] + c*c; \
                    }                                                        \
                }                                                            \
            }                                                                \
        }                                                                    \
    }

#define EPILOGUE_STORE(X0)                                                   \
    _Pragma("unroll")                                                        \
    for (int k = 0; k < 4; ++k) {                                            \
        float2 o;                                                            \
        _Pragma("unroll")                                                    \
        for (int j = 0; j < 2; ++j) {                                        \
            float m1 = s1[k][j] * 0.04f;                                     \
            float e1 = q1[k][j] * 0.04f;                                     \
            float m2 = s2[k][j] * 0.04f;                                     \
            float e2 = q2[k][j] * 0.04f;                                     \
            float var1 = fmaxf(e1 - m1 * m1, 0.0f);                          \
            float sd1 = sqrtf(var1 + 1e-9f);                                 \
            float var2 = fmaxf(e2 - m2 * m2, 0.0f);                          \
            float sd2 = sqrtf(var2 + 1e-9f);                                 \
            float num = (2.0f * sd1) * sd2;                                  \
            float den = ((sd1 * sd1 + sd2 * sd2) + 1e-5f) + 1e-8f;           \
            float val = (num / den > 0.975f) ? 1.0f : 0.0f;                  \
            (j == 0 ? o.x : o.y) = val;                                      \
        }                                                                    \
        size_t oidx = ((size_t)b * IMG_H + (y0 + r0 + k)) * IMG_W            \
                      + ((X0) + cb);                                         \
        *reinterpret_cast<float2*>(&out[oidx]) = o;                          \
    }

// Block = two 64x64 tiles, double-buffered LDS. Tile-B staging loads are
// ISSUED early (one 6xfloat4 batch in flight) and their LDS writes happen
// late, so HBM latency hides under tile-A's mandatory fold chains (T14).
__global__ __launch_bounds__(NTHREADS) void texdiff_kernel(
        const float* __restrict__ img1,
        const float* __restrict__ img2,
        float* __restrict__ out) {
    __shared__ float2 g12[2][LROWS][LCOLS];   // 2 x 38,080 B

    const int b   = blockIdx.z;
    const int y0  = blockIdx.y * TILE;
    const int x0a = blockIdx.x * (2 * TILE);
    const int x0b = x0a + TILE;
    const int tid = threadIdx.x;

    const size_t plane = (size_t)IMG_H * IMG_W;
    const float* i1 = img1 + (size_t)b * 3 * plane;
    const float* i2 = img2 + (size_t)b * 3 * plane;

    stage_tile(g12[0], i1, i2, x0a, y0, tid);
    __syncthreads();

    const int cx = tid & 31;
    const int ry = tid >> 5;
    const int r0 = ry * 4;
    const int cb = 2 * cx;

    float s1[4][2], q1[4][2], s2[4][2], q2[4][2];
    #pragma unroll
    for (int k = 0; k < 4; ++k) {
        #pragma unroll
        for (int j = 0; j < 2; ++j) {
            s1[k][j] = 0.0f; q1[k][j] = 0.0f;
            s2[k][j] = 0.0f; q2[k][j] = 0.0f;
        }
    }

    // ---- pipelined: stage B (issue-early/write-late) under compute A ----
    Quad Q;
    load_quad(Q, i1, i2, x0b, y0, tid);                 // P0 in flight
    FOLD_ROW(g12[0], 0)
    FOLD_ROW(g12[0], 1)
    write_quad(g12[1], Q, tid);                         // W0
    load_quad(Q, i1, i2, x0b, y0, tid + NTHREADS);      // P1 in flight
    FOLD_ROW(g12[0], 2)
    FOLD_ROW(g12[0], 3)
    write_quad(g12[1], Q, tid + NTHREADS);              // W1
    // P2: tail quad + halo (predicated)
    Quad Qt;
    if (tid < 64) load_quad(Qt, i1, i2, x0b, y0, tid + 2 * NTHREADS);
    float h0 = 0, h1 = 0, h2 = 0, h3 = 0, h4 = 0, h5 = 0;
    int hr = 0, hc = 0;
    if (tid < 272) {
        hr = tid >> 2;
        int s = tid & 3;
        hc = (s < 2) ? s : (s + 64);
        int gy = reflect_idx(y0 + hr - PAD);
        int gx = reflect_idx(x0b + hc - PAD);
        size_t off = (size_t)gy * IMG_W + gx;
        h0 = i1[off]; h1 = i1[off + plane]; h2 = i1[off + 2 * plane];
        h3 = i2[off]; h4 = i2[off + plane]; h5 = i2[off + 2 * plane];
    }
    FOLD_ROW(g12[0], 4)
    FOLD_ROW(g12[0], 5)
    if (tid < 64)  write_quad(g12[1], Qt, tid + 2 * NTHREADS);   // W2
    if (tid < 272) g12[1][hr][hc] = gray2(h0, h1, h2, h3, h4, h5);
    FOLD_ROW(g12[0], 6)
    FOLD_ROW(g12[0], 7)
    EPILOGUE_STORE(x0a)

    __syncthreads();

    // ---- compute tile B (already staged) ----
    #pragma unroll
    for (int k = 0; k < 4; ++k) {
        #pragma unroll
        for (int j = 0; j < 2; ++j) {
            s1[k][j] = 0.0f; q1[k][j] = 0.0f;
            s2[k][j] = 0.0f; q2[k][j] = 0.0f;
        }
    }
    FOLD_ROW(g12[1], 0)
    FOLD_ROW(g12[1], 1)
    FOLD_ROW(g12[1], 2)
    FOLD_ROW(g12[1], 3)
    FOLD_ROW(g12[1], 4)
    FOLD_ROW(g12[1], 5)
    FOLD_ROW(g12[1], 6)
    FOLD_ROW(g12[1], 7)
    EPILOGUE_STORE(x0b)
}

extern "C" void kernel_launch(void* const* d_in, const int* in_sizes, int n_in,
                              void* d_out, int out_size, void* d_ws, size_t ws_size,
                              hipStream_t stream) {
    const float* img1 = (const float*)d_in[0];
    const float* img2 = (const float*)d_in[1];
    float* out = (float*)d_out;
    dim3 grid(IMG_W / (2 * TILE), IMG_H / TILE, 16);   // 4 x 8 x 16 = 512 blocks
    texdiff_kernel<<<grid, dim3(NTHREADS), 0, stream>>>(img1, img2, out);
}

// Round 5
// 133.100 us; speedup vs baseline: 1.3465x; 1.0867x over previous
//
#include <hip/hip_runtime.h>

#pragma clang fp contract(off)

#define IMG_H 512
#define IMG_W 512
#define TILE_W 64
#define TILE_H 32
#define PAD 2
#define LROWS 36                 // TILE_H + 2*PAD
#define LCOLS 70                 // padded float2 width (2 + 64 + 2 = 68, pad to 70)
#define NTHREADS 256

__device__ __forceinline__ int reflect_idx(int i) {
    // jnp.pad 'reflect': -1 -> 1, 512 -> 510
    i = (i < 0) ? -i : i;
    i = (i >= IMG_H) ? (2 * IMG_H - 2 - i) : i;
    return i;
}

__device__ __forceinline__ float2 gray2(float a0, float a1, float a2,
                                        float b0, float b1, float b2) {
    // bit-identical T_a gray conversion (verified absmax=0.0)
    float2 g;
    g.x = (0.144f * a0 + 0.587f * a1) + 0.299f * a2;
    g.y = (0.144f * b0 + 0.587f * b1) + 0.299f * b2;
    return g;
}

// Stage one 36x68 halo tile of interleaved (gray1,gray2) pairs into LDS.
// Interior: 36 rows x 16 quads = 576 items (2 full passes + 64-thread tail),
// aligned float4 global loads (x0 % 64 == 0). The two main-pass quads'
// 12 dwordx4 loads are issued back-to-back (single latency exposure; this
// exact shape compiled to 84 VGPR with no spill in R2).
// Halo: 36 rows x 4 cols = 144 scalar items (handles reflect).
__device__ __forceinline__ void stage_tile(float2 (*buf)[LCOLS],
        const float* __restrict__ i1, const float* __restrict__ i2,
        int x0, int y0, int tid) {
    const size_t plane = (size_t)IMG_H * IMG_W;

    int it0 = tid;                 // rows 0..15
    int it1 = tid + NTHREADS;      // rows 16..31
    int r0 = it0 >> 4, q0 = it0 & 15;
    int r1 = it1 >> 4, q1 = it1 & 15;
    int gy0 = reflect_idx(y0 + r0 - PAD);
    int gy1 = reflect_idx(y0 + r1 - PAD);
    const float* pa0 = i1 + (size_t)gy0 * IMG_W + (x0 + 4 * q0);
    const float* pb0 = i2 + (size_t)gy0 * IMG_W + (x0 + 4 * q0);
    const float* pa1 = i1 + (size_t)gy1 * IMG_W + (x0 + 4 * q1);
    const float* pb1 = i2 + (size_t)gy1 * IMG_W + (x0 + 4 * q1);

    float4 A0 = *(const float4*)(pa0);
    float4 A1 = *(const float4*)(pa0 + plane);
    float4 A2 = *(const float4*)(pa0 + 2 * plane);
    float4 B0 = *(const float4*)(pb0);
    float4 B1 = *(const float4*)(pb0 + plane);
    float4 B2 = *(const float4*)(pb0 + 2 * plane);
    float4 C0 = *(const float4*)(pa1);
    float4 C1 = *(const float4*)(pa1 + plane);
    float4 C2 = *(const float4*)(pa1 + 2 * plane);
    float4 D0 = *(const float4*)(pb1);
    float4 D1 = *(const float4*)(pb1 + plane);
    float4 D2 = *(const float4*)(pb1 + 2 * plane);

    {
        float2 g0 = gray2(A0.x, A1.x, A2.x, B0.x, B1.x, B2.x);
        float2 g1 = gray2(A0.y, A1.y, A2.y, B0.y, B1.y, B2.y);
        float2 g2 = gray2(A0.z, A1.z, A2.z, B0.z, B1.z, B2.z);
        float2 g3 = gray2(A0.w, A1.w, A2.w, B0.w, B1.w, B2.w);
        float4* dst = (float4*)&buf[r0][2 + 4 * q0];   // 16B-aligned
        dst[0] = make_float4(g0.x, g0.y, g1.x, g1.y);
        dst[1] = make_float4(g2.x, g2.y, g3.x, g3.y);
    }
    {
        float2 g0 = gray2(C0.x, C1.x, C2.x, D0.x, D1.x, D2.x);
        float2 g1 = gray2(C0.y, C1.y, C2.y, D0.y, D1.y, D2.y);
        float2 g2 = gray2(C0.z, C1.z, C2.z, D0.z, D1.z, D2.z);
        float2 g3 = gray2(C0.w, C1.w, C2.w, D0.w, D1.w, D2.w);
        float4* dst = (float4*)&buf[r1][2 + 4 * q1];
        dst[0] = make_float4(g0.x, g0.y, g1.x, g1.y);
        dst[1] = make_float4(g2.x, g2.y, g3.x, g3.y);
    }

    if (tid < 64) {   // tail: rows 32..35
        int it2 = tid + 2 * NTHREADS;
        int r2 = it2 >> 4, q2 = it2 & 15;
        int gy2 = reflect_idx(y0 + r2 - PAD);
        const float* pa2 = i1 + (size_t)gy2 * IMG_W + (x0 + 4 * q2);
        const float* pb2 = i2 + (size_t)gy2 * IMG_W + (x0 + 4 * q2);
        float4 E0 = *(const float4*)(pa2);
        float4 E1 = *(const float4*)(pa2 + plane);
        float4 E2 = *(const float4*)(pa2 + 2 * plane);
        float4 F0 = *(const float4*)(pb2);
        float4 F1 = *(const float4*)(pb2 + plane);
        float4 F2 = *(const float4*)(pb2 + 2 * plane);
        float2 g0 = gray2(E0.x, E1.x, E2.x, F0.x, F1.x, F2.x);
        float2 g1 = gray2(E0.y, E1.y, E2.y, F0.y, F1.y, F2.y);
        float2 g2 = gray2(E0.z, E1.z, E2.z, F0.z, F1.z, F2.z);
        float2 g3 = gray2(E0.w, E1.w, E2.w, F0.w, F1.w, F2.w);
        float4* dst = (float4*)&buf[r2][2 + 4 * q2];
        dst[0] = make_float4(g0.x, g0.y, g1.x, g1.y);
        dst[1] = make_float4(g2.x, g2.y, g3.x, g3.y);
    }

    if (tid < 144) {   // halo: 36 rows x cols {0,1,66,67}
        int r = tid >> 2, s = tid & 3;
        int c = (s < 2) ? s : (s + 64);
        int gy = reflect_idx(y0 + r - PAD);
        int gx = reflect_idx(x0 + c - PAD);
        size_t off = (size_t)gy * IMG_W + gx;
        buf[r][c] = gray2(i1[off], i1[off + plane], i1[off + 2 * plane],
                          i2[off], i2[off + plane], i2[off + 2 * plane]);
    }
}

// T_a chains (verified absmax=0.0): rows ascend, dx ascends within row,
// acc starts 0.0f, mean via s*0.04f recip-mul. Bit-identical to R2/R4.
__global__ __launch_bounds__(NTHREADS) void texdiff_kernel(
        const float* __restrict__ img1,
        const float* __restrict__ img2,
        float* __restrict__ out) {
    __shared__ float2 g12[LROWS][LCOLS];   // 36*70*8 = 20,160 B

    const int b  = blockIdx.z;
    const int x0 = blockIdx.x * TILE_W;
    const int y0 = blockIdx.y * TILE_H;
    const int tid = threadIdx.x;

    const size_t plane = (size_t)IMG_H * IMG_W;
    const float* i1 = img1 + (size_t)b * 3 * plane;
    const float* i2 = img2 + (size_t)b * 3 * plane;

    stage_tile(g12, i1, i2, x0, y0, tid);
    __syncthreads();

    const int cx = tid & 31;       // col-pair: cols 2cx, 2cx+1
    const int ry = tid >> 5;       // 0..7 -> rows ry*4 .. ry*4+3
    const int r0 = ry * 4;
    const int cb = 2 * cx;

    float s1[4][2], q1[4][2], s2[4][2], q2[4][2];
    #pragma unroll
    for (int k = 0; k < 4; ++k) {
        #pragma unroll
        for (int j = 0; j < 2; ++j) {
            s1[k][j] = 0.0f; q1[k][j] = 0.0f;
            s2[k][j] = 0.0f; q2[k][j] = 0.0f;
        }
    }

    // 8 LDS rows serve 4 overlapping windows; each row read ONCE (3x b128).
    #pragma unroll
    for (int rr = 0; rr < 8; ++rr) {
        const float4* vp = (const float4*)&g12[r0 + rr][cb];  // 16B-aligned
        float4 w0 = vp[0], w1 = vp[1], w2 = vp[2];
        float vx[6], vy[6];
        vx[0] = w0.x; vy[0] = w0.y; vx[1] = w0.z; vy[1] = w0.w;
        vx[2] = w1.x; vy[2] = w1.y; vx[3] = w1.z; vy[3] = w1.w;
        vx[4] = w2.x; vy[4] = w2.y; vx[5] = w2.z; vy[5] = w2.w;

        #pragma unroll
        for (int k = 0; k < 4; ++k) {
            if (rr >= k && rr <= k + 4) {   // compile-time predicate
                #pragma unroll
                for (int j = 0; j < 2; ++j) {
                    #pragma unroll
                    for (int dx = 0; dx < 5; ++dx) {
                        float a = vx[dx + j];
                        float c = vy[dx + j];
                        s1[k][j] = s1[k][j] + a;  q1[k][j] = q1[k][j] + a * a;
                        s2[k][j] = s2[k][j] + c;  q2[k][j] = q2[k][j] + c * c;
                    }
                }
            }
        }
    }

    #pragma unroll
    for (int k = 0; k < 4; ++k) {
        float2 o;
        #pragma unroll
        for (int j = 0; j < 2; ++j) {
            float m1 = s1[k][j] * 0.04f;
            float e1 = q1[k][j] * 0.04f;
            float m2 = s2[k][j] * 0.04f;
            float e2 = q2[k][j] * 0.04f;
            float var1 = fmaxf(e1 - m1 * m1, 0.0f);
            float sd1 = sqrtf(var1 + 1e-9f);
            float var2 = fmaxf(e2 - m2 * m2, 0.0f);
            float sd2 = sqrtf(var2 + 1e-9f);
            float num = (2.0f * sd1) * sd2;
            float den = ((sd1 * sd1 + sd2 * sd2) + 1e-5f) + 1e-8f;
            float val = (num / den > 0.975f) ? 1.0f : 0.0f;
            (j == 0 ? o.x : o.y) = val;
        }
        size_t oidx = ((size_t)b * IMG_H + (y0 + r0 + k)) * IMG_W + (x0 + cb);
        *reinterpret_cast<float2*>(&out[oidx]) = o;
    }
}

extern "C" void kernel_launch(void* const* d_in, const int* in_sizes, int n_in,
                              void* d_out, int out_size, void* d_ws, size_t ws_size,
                              hipStream_t stream) {
    const float* img1 = (const float*)d_in[0];
    const float* img2 = (const float*)d_in[1];
    float* out = (float*)d_out;
    dim3 grid(IMG_W / TILE_W, IMG_H / TILE_H, 16);   // 8 x 16 x 16 = 2048 blocks
    texdiff_kernel<<<grid, dim3(NTHREADS), 0, stream>>>(img1, img2, out);
}